// Round 11
// baseline (116.265 us; speedup 1.0000x reference)
//
#include <hip/hip_runtime.h>
#include <math.h>

#define DIM    4096      // 2^12
#define NB     1024      // batch
#define SPAD   4160      // phys(i) = i + (i>>6); max 4095+63 = 4158

typedef float v2f __attribute__((ext_vector_type(2)));
typedef unsigned long long ull;

// Fused (Ry*Rx) SU(2) gate on reg bit G of a 64-amp block, complex interleaved.
// P1=(cc,cs), P2=(ss,sc); 8 v_pk ops per pair. [HW-verified R4-R9]
template<int G>
__device__ __forceinline__ void gate_pk64(v2f (&x)[64], v2f P1, v2f P2) {
#pragma unroll
    for (int p = 0; p < 32; ++p) {
        const int j0 = ((p >> G) << (G + 1)) | (p & ((1 << G) - 1));
        const int j1 = j0 | (1 << G);
        const v2f x0 = x[j0], x1 = x[j1];
        v2f t, u;
        asm("v_pk_mul_f32 %0, %1, %2 op_sel:[1,1] op_sel_hi:[1,0] neg_hi:[1,0]"
            : "=v"(t) : "v"(P2), "v"(x1));
        asm("v_pk_fma_f32 %0, %1, %2, %0 op_sel:[1,0,0] op_sel_hi:[1,1,1] neg_lo:[1,0,0] neg_hi:[1,0,0]"
            : "+v"(t) : "v"(P1), "v"(x1));
        asm("v_pk_fma_f32 %0, %1, %2, %0 op_sel:[0,1,0] op_sel_hi:[0,0,1] neg_lo:[1,0,0]"
            : "+v"(t) : "v"(P2), "v"(x0));
        asm("v_pk_fma_f32 %0, %1, %2, %0 op_sel:[0,0,0] op_sel_hi:[0,1,1]"
            : "+v"(t) : "v"(P1), "v"(x0));
        asm("v_pk_mul_f32 %0, %1, %2 op_sel:[0,1] op_sel_hi:[0,0] neg_hi:[1,0]"
            : "=v"(u) : "v"(P2), "v"(x1));
        asm("v_pk_fma_f32 %0, %1, %2, %0 op_sel:[0,0,0] op_sel_hi:[0,1,1]"
            : "+v"(u) : "v"(P1), "v"(x1));
        asm("v_pk_fma_f32 %0, %1, %2, %0 op_sel:[1,1,0] op_sel_hi:[1,0,1] neg_hi:[1,0,0]"
            : "+v"(u) : "v"(P2), "v"(x0));
        asm("v_pk_fma_f32 %0, %1, %2, %0 op_sel:[1,0,0] op_sel_hi:[1,1,1]"
            : "+v"(u) : "v"(P1), "v"(x0));
        x[j0] = t; x[j1] = u;
    }
}

// CZ diagonal via per-thread 64-bit sign mask (bit j -> reg j). [R8 structure]
__device__ __forceinline__ void applyCZ64(v2f (&x)[64], ull mask) {
#pragma unroll
    for (int j = 0; j < 64; ++j) {
        const unsigned w = (j < 32) ? (unsigned)mask : (unsigned)(mask >> 32);
        const unsigned sw = (w << (31 - (j & 31))) & 0x80000000u;
        x[j].x = __uint_as_float(__float_as_uint(x[j].x) ^ sw);
        x[j].y = __uint_as_float(__float_as_uint(x[j].y) ^ sw);
    }
}

// bit v of KPAR = parity(popc(v & (v>>1) & 0x1F)) for 6-bit v. [HW-verified R8]
#define KPAR 0xB8B7B8484748B848ULL

// One wave (64 threads) per sample; thread l holds 64 amps.
//   Q layout: reg j = amp l*64+j  -> phys 65l+j (thread-contiguous)
//   P layout: reg j = amp j*64+l  -> phys 65j+l (lane-contiguous)
// Schedule (rolled, k=0..7): Q0 |T| P0+Z0 | P1 |T| Q1+Z1 | Q2 |T| P2+Z2 | P3
// |T| Q3+Z3.  4 transposes, 0 barriers, ~17 KB loop body (L1I-resident).
__global__ __launch_bounds__(64, 1) void qddpm_kernel(
    const float* __restrict__ in_re,
    const float* __restrict__ in_im,
    const float* __restrict__ params,
    const float* __restrict__ uu,
    float* __restrict__ out)
{
    __shared__ v2f    S[SPAD];         // 33.3 KB staging
    __shared__ float4 gco[48];         // per-gate (cc, cs, ss, sc)
    __shared__ float  sprob[16];

    const int b = blockIdx.x;
    const int l = threadIdx.x;         // lane 0..63
    const float uval = uu[b];

    v2f x[64];
    // ---- global -> regs, Q layout (512 contiguous B per thread) ----
    {
        const float4* re4 = (const float4*)(in_re + (size_t)b * DIM + l * 64);
        const float4* im4 = (const float4*)(in_im + (size_t)b * DIM + l * 64);
#pragma unroll
        for (int q = 0; q < 16; ++q) {
            const float4 vr = re4[q];
            const float4 vi = im4[q];
            x[4 * q + 0] = (v2f){vr.x, vi.x};
            x[4 * q + 1] = (v2f){vr.y, vi.y};
            x[4 * q + 2] = (v2f){vr.z, vi.z};
            x[4 * q + 3] = (v2f){vr.w, vi.w};
        }
    }
    // ---- gate coeffs (single wave: lgkm-ordered, no barrier) ----
    if (l < 48) {
        const int lay = l / 12, q = l - lay * 12;
        float c1, s1, c2, s2;
        sincosf(params[lay * 24 + q] * 0.5f, &s1, &c1);
        sincosf(params[lay * 24 + 12 + q] * 0.5f, &s2, &c2);
        gco[l] = make_float4(c1 * c2, c1 * s2, s1 * s2, s1 * c2); // (cc,cs,ss,sc)
    }
    // ---- CZ masks: par(i) = f(lo6) ^ f(hi6) ^ (lo5&hi0), f = KPAR bits ----
    const ull parl  = ((KPAR >> l) & 1ULL) ? ~0ULL : 0ULL;
    const ull maskQ = KPAR ^ parl ^ ((l & 1)  ? 0xFFFFFFFF00000000ULL : 0ULL);
    const ull maskP = KPAR ^ parl ^ ((l & 32) ? 0xAAAAAAAAAAAAAAAAULL : 0ULL);

#pragma unroll 1                       // keep ONE 17KB body resident in L1I
    for (int k = 0; k < 8; ++k) {
        const int isQ = (~(k ^ (k >> 1))) & 1;   // {1,0,0,1,1,0,0,1}
        if (k & 1) {                   // transpose to this call's layout
            if (!isQ) {                // Q -> P
#pragma unroll
                for (int j = 0; j < 64; ++j) S[65 * l + j] = x[j];
#pragma unroll
                for (int j = 0; j < 64; ++j) x[j] = S[65 * j + l];
            } else {                   // P -> Q
#pragma unroll
                for (int j = 0; j < 64; ++j) S[65 * j + l] = x[j];
#pragma unroll
                for (int j = 0; j < 64; ++j) x[j] = S[65 * l + j];
            }
        }
        // 6 gates of layer k>>1 on this partition (reg bit g -> gco[top-g])
        const int top = 12 * (k >> 1) + (isQ ? 11 : 5);
        { float4 c;
          c = gco[top - 0]; gate_pk64<0>(x, (v2f){c.x, c.y}, (v2f){c.z, c.w});
          c = gco[top - 1]; gate_pk64<1>(x, (v2f){c.x, c.y}, (v2f){c.z, c.w});
          c = gco[top - 2]; gate_pk64<2>(x, (v2f){c.x, c.y}, (v2f){c.z, c.w});
          c = gco[top - 3]; gate_pk64<3>(x, (v2f){c.x, c.y}, (v2f){c.z, c.w});
          c = gco[top - 4]; gate_pk64<4>(x, (v2f){c.x, c.y}, (v2f){c.z, c.w});
          c = gco[top - 5]; gate_pk64<5>(x, (v2f){c.x, c.y}, (v2f){c.z, c.w}); }
        if (k & 1)                     // layer complete -> CZ diagonal
            applyCZ64(x, isQ ? maskQ : maskP);
    }

    // ---- epilogue (Q layout): stage state, probs, sample, emit ----
#pragma unroll
    for (int j = 0; j < 64; ++j) S[65 * l + j] = x[j];
    {
        v2f a2 = (v2f){0.0f, 0.0f};
#pragma unroll
        for (int j = 0; j < 64; ++j) a2 += x[j] * x[j];
        float p = a2.x + a2.y;         // thread's amps all in outcome l>>2
        p += __shfl_down(p, 2, 4);
        p += __shfl_down(p, 1, 4);
        if ((l & 3) == 0) sprob[l >> 2] = p;
    }
    {
        float cdf[16];
        float a = 0.0f;
#pragma unroll
        for (int i = 0; i < 16; ++i) { a += sprob[i]; cdf[i] = a; }
        const float thresh = uval * a;
        int m = 0;
#pragma unroll
        for (int i = 15; i >= 0; --i) { if (cdf[i] >= thresh) m = i; }
        const float rn = 1.0f / sqrtf(sprob[m]);
        float2* o2 = (float2*)out + (size_t)b * 256;
#pragma unroll
        for (int q = 0; q < 4; ++q) {  // amp m*256+q*64+l -> phys 260m+65q+l
            const v2f amp = S[260 * m + 65 * q + l];
            o2[q * 64 + l] = make_float2(amp.x * rn, amp.y * rn);
        }
    }
}

extern "C" void kernel_launch(void* const* d_in, const int* in_sizes, int n_in,
                              void* d_out, int out_size, void* d_ws, size_t ws_size,
                              hipStream_t stream) {
    const float* in_re  = (const float*)d_in[0];
    const float* in_im  = (const float*)d_in[1];
    const float* params = (const float*)d_in[2];
    const float* u      = (const float*)d_in[3];
    float* out = (float*)d_out;
    qddpm_kernel<<<NB, 64, 0, stream>>>(in_re, in_im, params, u, out);
}